// Round 5
// baseline (4807.615 us; speedup 1.0000x reference)
//
#include <hip/hip_runtime.h>
#include <math.h>

// ---------------------------------------------------------------------------
// DisableGateLSTM: 512-step LSTM over 64 independent chains.
// 256 blocks x 512 threads, 1 block/CU. 4 groups x 64 blocks; group g owns
// chains [16g,16g+16); block j owns hidden units [8j,8j+8) = 32 gate rows.
// Weights LDS-resident. Cross-block h exchange: relaxed agent-scope atomics.
// R5: parallel per-block FLAG barrier (no serialized RMW), x-GEMM overlapped
// ahead of the poll, reduction+gates fused. Gates use exact libm expf/tanhf.
// ---------------------------------------------------------------------------

#define BATCH   64
#define SEQ     512
#define EMBED   256
#define HIDDEN  512
#define GD      768
#define CLASSES 4

#define NBLK    256
#define NTHR    512
#define GROUPS  4
#define GB      64
#define CPG     16
#define UPB     8
#define ROWS    32

#define SWHS 532
#define SWXS 276
#define SHS  544
#define SXS  268

__global__ __launch_bounds__(NTHR, 1) void lstm_persistent(
    const int*   __restrict__ ids,
    const float* __restrict__ emb,
    const float* __restrict__ Wf, const float* __restrict__ bf,
    const float* __restrict__ Wi, const float* __restrict__ bi,
    const float* __restrict__ Wo, const float* __restrict__ bo,
    const float* __restrict__ Wc, const float* __restrict__ bc,
    const float* __restrict__ fcw,
    const float* __restrict__ fcb,
    float* __restrict__ out,
    float* __restrict__ ws)
{
  __shared__ __align__(16) float sWh[ROWS * SWHS];
  __shared__ __align__(16) float sWx[ROWS * SWXS];
  __shared__ __align__(16) float sH [CPG * SHS];     // also 512*17 reduce scratch
  __shared__ __align__(16) float sX [CPG * SXS];
  __shared__ float sG[ROWS][CPG];                    // head-GEMV scratch only
  __shared__ float sC[UPB][CPG];
  __shared__ float sM[UPB][CPG];
  __shared__ float sB[ROWS];

  const int tid = threadIdx.x;
  const int bid = blockIdx.x;
  const int g   = bid & 3;
  const int j   = bid >> 2;
  const int u0  = j * UPB;

  float*    hbuf  = ws;                                   // [2][64][512] float
  float*    wmax  = ws + (size_t)2 * BATCH * HIDDEN;      // [64][512]
  unsigned* flags = (unsigned*)(ws + (size_t)3 * BATCH * HIDDEN) + g * 1024;
  // block j's slot: flags[j*16] (64B apart). Monotone values, no resets.

  // ---- weights -> LDS (skewed layout), once ----
  for (int r = 0; r < ROWS; ++r) {
    const float* W = (r < 8) ? Wf : (r < 16) ? Wi : (r < 24) ? Wo : Wc;
    const float* src = W + (size_t)(u0 + (r & 7)) * GD;
    const int skw = ((r >> 3) & 3) * 4;
    float* dh = sWh + r * SWHS + skw;
    float* dx = sWx + r * SWXS + skw;
    for (int col = tid; col < GD; col += NTHR) {
      float v = src[col];
      if (col < HIDDEN) dh[col] = v;
      else              dx[col - HIDDEN] = v;
    }
  }
  if (tid < ROWS) {
    const float* bv = (tid < 8) ? bf : (tid < 16) ? bi : (tid < 24) ? bo : bc;
    sB[tid] = bv[u0 + (tid & 7)];
  }
  if (tid < UPB * CPG) {
    ((float*)sC)[tid] = 0.0f;
    ((float*)sM)[tid] = -3.402823e38f;
  }

  // GEMM thread tiling: acc[4 rows][4 chains], K split 16 ways
  const int cg = tid & 3;
  const int rg = (tid >> 2) & 7;
  const int ks = tid >> 5;

  const int stg_c = tid >> 5;      // staging chain 0..15
  const int stg_s = tid & 31;      // staging lane
  const int bStg  = g * CPG + stg_c;

  const float* pH0  = sH  + (cg * 4) * SHS  + cg * 4;
  const float* pX0  = sX  + (cg * 4) * SXS  + cg * 4;
  const float* pW0  = sWh + (rg * 4) * SWHS + ((rg >> 1) & 3) * 4;
  const float* pWx0 = sWx + (rg * 4) * SWXS + ((rg >> 1) & 3) * 4;

  // prefetch x_0 into registers
  float4 rx0, rx1;
  {
    int id0 = ids[(size_t)bStg * SEQ];
    const float4* xs = (const float4*)(emb + (size_t)id0 * EMBED);
    rx0 = xs[stg_s * 2];
    rx1 = xs[stg_s * 2 + 1];
  }

  for (int t = 0; t < SEQ; ++t) {
    const int pb = t & 1;

    // ---- write x_t into sX; prefetch x_{t+1} (overlaps everything below) ----
    {
      float* dx = sX + stg_c * SXS + ((stg_c >> 2) & 3) * 4 + stg_s * 8;
      *(float4*)dx = rx0;
      *(float4*)(dx + 4) = rx1;
    }
    {
      const int tn = (t + 1 < SEQ) ? t + 1 : SEQ - 1;
      int idn = ids[(size_t)bStg * SEQ + tn];
      const float4* xs = (const float4*)(emb + (size_t)idn * EMBED);
      rx0 = xs[stg_s * 2];
      rx1 = xs[stg_s * 2 + 1];
    }
    __syncthreads();

    // ---- x-GEMM first: h-independent, runs while other blocks finish h_t ----
    float acc[4][4];
    #pragma unroll
    for (int a = 0; a < 4; ++a)
      #pragma unroll
      for (int b2 = 0; b2 < 4; ++b2) acc[a][b2] = 0.0f;
    {
      const float* px  = pX0 + ks * 16;
      const float* pwx = pWx0 + ks * 16;
      #pragma unroll
      for (int kk = 0; kk < 4; ++kk) {
        float4 xv[4], wv[4];
        #pragma unroll
        for (int ci = 0; ci < 4; ++ci)
          xv[ci] = *(const float4*)(px + ci * SXS + kk * 4);
        #pragma unroll
        for (int ri = 0; ri < 4; ++ri)
          wv[ri] = *(const float4*)(pwx + ri * SWXS + kk * 4);
        #pragma unroll
        for (int ri = 0; ri < 4; ++ri)
          #pragma unroll
          for (int ci = 0; ci < 4; ++ci) {
            acc[ri][ci] = fmaf(wv[ri].x, xv[ci].x, acc[ri][ci]);
            acc[ri][ci] = fmaf(wv[ri].y, xv[ci].y, acc[ri][ci]);
            acc[ri][ci] = fmaf(wv[ri].z, xv[ci].z, acc[ri][ci]);
            acc[ri][ci] = fmaf(wv[ri].w, xv[ci].w, acc[ri][ci]);
          }
      }
    }

    // ---- parallel-flag barrier: wait until all 64 blocks published h_t ----
    if (tid < 64) {
      const unsigned* fp = flags + tid * 16;
      for (;;) {
        unsigned v = __hip_atomic_load(fp, __ATOMIC_RELAXED,
                                       __HIP_MEMORY_SCOPE_AGENT);
        if (__all((int)(v >= (unsigned)t))) break;
        __builtin_amdgcn_s_sleep(1);
      }
    }
    __atomic_signal_fence(__ATOMIC_ACQUIRE);
    __syncthreads();

    // ---- stage h_t via coherent loads ----
    {
      const float* hs = hbuf + ((size_t)pb * BATCH + bStg) * HIDDEN;
      float* dh = sH + stg_c * SHS + ((stg_c >> 2) & 3) * 4;
      #pragma unroll
      for (int kk = 0; kk < 16; ++kk) {
        float v = __hip_atomic_load(hs + stg_s + kk * 32, __ATOMIC_RELAXED,
                                    __HIP_MEMORY_SCOPE_AGENT);
        dh[stg_s + kk * 32] = v;
      }
    }
    __syncthreads();

    // ---- h-GEMM ----
    {
      const float* ph = pH0 + ks * 32;
      const float* pw = pW0 + ks * 32;
      #pragma unroll
      for (int kk = 0; kk < 8; ++kk) {
        float4 hv[4], wv[4];
        #pragma unroll
        for (int ci = 0; ci < 4; ++ci)
          hv[ci] = *(const float4*)(ph + ci * SHS + kk * 4);
        #pragma unroll
        for (int ri = 0; ri < 4; ++ri)
          wv[ri] = *(const float4*)(pw + ri * SWHS + kk * 4);
        #pragma unroll
        for (int ri = 0; ri < 4; ++ri)
          #pragma unroll
          for (int ci = 0; ci < 4; ++ci) {
            acc[ri][ci] = fmaf(wv[ri].x, hv[ci].x, acc[ri][ci]);
            acc[ri][ci] = fmaf(wv[ri].y, hv[ci].y, acc[ri][ci]);
            acc[ri][ci] = fmaf(wv[ri].z, hv[ci].z, acc[ri][ci]);
            acc[ri][ci] = fmaf(wv[ri].w, hv[ci].w, acc[ri][ci]);
          }
      }
    }
    __syncthreads();                 // done reading sH; reuse as reduce scratch

    // ---- k-split partials -> scratch ----
    float* red = sH;
    {
      const int rank = ks * 32 + rg * 4 + cg;
      #pragma unroll
      for (int ri = 0; ri < 4; ++ri)
        #pragma unroll
        for (int ci = 0; ci < 4; ++ci)
          red[rank * 17 + ri * 4 + ci] = acc[ri][ci];
    }
    __syncthreads();

    // ---- fused reduction + gates + h store (128 threads, 1 unit each) ----
    if (tid < UPB * CPG) {
      const int uu = tid >> 4, ch = tid & 15;
      const int sub = (uu & 3) * 4 + (ch & 3);
      float s[4];
      #pragma unroll
      for (int ga = 0; ga < 4; ++ga) {
        const int row = ga * 8 + uu;
        const int base = (row >> 2) * 4 + (ch >> 2);
        float a = sB[row];
        #pragma unroll
        for (int q = 0; q < 16; ++q)
          a += red[(q * 32 + base) * 17 + sub];
        s[ga] = a;
      }
      float f  = 1.0f / (1.0f + expf(-s[0]));
      float i_ = 1.0f / (1.0f + expf(-s[1]));
      float o  = 1.0f / (1.0f + expf(-s[2]));
      float gg = tanhf(s[3]);
      float cn = f * sC[uu][ch] + i_ * gg;
      float h  = o * tanhf(cn);
      sC[uu][ch] = cn;
      sM[uu][ch] = fmaxf(sM[uu][ch], h);
      __hip_atomic_store(
          hbuf + ((size_t)(pb ^ 1) * BATCH + g * CPG + ch) * HIDDEN + u0 + uu,
          h, __ATOMIC_RELAXED, __HIP_MEMORY_SCOPE_AGENT);
    }
    __syncthreads();   // drains vmcnt on all waves -> h stores visible

    // ---- arrival: one parallel store, zero RMWs ----
    if (tid == 0)
      __hip_atomic_store(flags + j * 16, (unsigned)(t + 1), __ATOMIC_RELAXED,
                         __HIP_MEMORY_SCOPE_AGENT);
  }

  // ---- publish running max, signal SEQ+1 ----
  if (tid < UPB * CPG) {
    const int uu = tid >> 4, ch = tid & 15;
    __hip_atomic_store(
        wmax + (size_t)(g * CPG + ch) * HIDDEN + u0 + uu,
        sM[uu][ch], __ATOMIC_RELAXED, __HIP_MEMORY_SCOPE_AGENT);
  }
  __syncthreads();
  if (tid == 0)
    __hip_atomic_store(flags + j * 16, (unsigned)(SEQ + 1), __ATOMIC_RELAXED,
                       __HIP_MEMORY_SCOPE_AGENT);

  // ---- head GEMV on group-leader blocks ----
  if (j == 0) {
    if (tid < 64) {
      const unsigned* fp = flags + tid * 16;
      for (;;) {
        unsigned v = __hip_atomic_load(fp, __ATOMIC_RELAXED,
                                       __HIP_MEMORY_SCOPE_AGENT);
        if (__all((int)(v >= (unsigned)(SEQ + 1)))) break;
        __builtin_amdgcn_s_sleep(1);
      }
    }
    __atomic_signal_fence(__ATOMIC_ACQUIRE);
    __syncthreads();

    const int ch = tid & 15, cls = (tid >> 4) & 3, us = tid >> 6;
    const float* mrow = wmax + (size_t)(g * CPG + ch) * HIDDEN + us * 64;
    const float* wrow = fcw + (size_t)cls * HIDDEN + us * 64;
    float s = 0.0f;
    for (int q = 0; q < 64; ++q) {
      float v = __hip_atomic_load(mrow + q, __ATOMIC_RELAXED,
                                  __HIP_MEMORY_SCOPE_AGENT);
      s = fmaf(v, wrow[q], s);
    }
    float* red2 = &sG[0][0];
    red2[tid] = s;
    __syncthreads();
    if (tid < 64) {
      float tot = fcb[(tid >> 4) & 3];
      #pragma unroll
      for (int q = 0; q < 8; ++q) tot += red2[q * 64 + tid];
      out[(g * CPG + (tid & 15)) * CLASSES + ((tid >> 4) & 3)] = tot;
    }
  }
}

extern "C" void kernel_launch(void* const* d_in, const int* in_sizes, int n_in,
                              void* d_out, int out_size, void* d_ws, size_t ws_size,
                              hipStream_t stream) {
  const int*   ids = (const int*)  d_in[0];
  const float* emb = (const float*)d_in[1];
  const float* Wf  = (const float*)d_in[2];
  const float* bf  = (const float*)d_in[3];
  const float* Wi  = (const float*)d_in[4];
  const float* bi  = (const float*)d_in[5];
  const float* Wo  = (const float*)d_in[6];
  const float* bo  = (const float*)d_in[7];
  const float* Wc  = (const float*)d_in[8];
  const float* bc  = (const float*)d_in[9];
  const float* fcw = (const float*)d_in[10];
  const float* fcb = (const float*)d_in[11];

  // zero h0 (hbuf buffer 0) and the flag area (4 groups x 4KB)
  hipMemsetAsync(d_ws, 0, (size_t)BATCH * HIDDEN * sizeof(float), stream);
  hipMemsetAsync((char*)d_ws + (size_t)3 * BATCH * HIDDEN * sizeof(float),
                 0, GROUPS * 4096, stream);

  lstm_persistent<<<dim3(NBLK), dim3(NTHR), 0, stream>>>(
      ids, emb, Wf, bf, Wi, bi, Wo, bo, Wc, bc, fcw, fcb,
      (float*)d_out, (float*)d_ws);
}